// Round 1
// baseline (7279.481 us; speedup 1.0000x reference)
//
#include <hip/hip_runtime.h>

#define NN 100000
#define NE 1600000
#define NG 64

static inline int cdiv(int a, int b) { return (a + b - 1) / b; }

// ---- degree ------------------------------------------------------------
__global__ void deg_kernel(const int* __restrict__ dst, float* __restrict__ deg, int E) {
    int e = blockIdx.x * blockDim.x + threadIdx.x;
    if (e < E) unsafeAtomicAdd(&deg[dst[e]], 1.0f);
}

__global__ void ideg_kernel(float* __restrict__ deg, int N) {
    int n = blockIdx.x * blockDim.x + threadIdx.x;
    if (n < N) deg[n] = 1.0f / fmaxf(deg[n], 1.0f);
}

// ---- fused dual GEMM: P = h@Wl, Q = h@Wr + b ---------------------------
// h: [N][128], Wl/Wr: [128][OUT] row-major, P/Q: [N][OUT]
template <int OUT>
__global__ __launch_bounds__(256) void sage_gemm(
    const float* __restrict__ h, const float* __restrict__ Wl,
    const float* __restrict__ Wr, const float* __restrict__ bias,
    float* __restrict__ P, float* __restrict__ Q, int N) {
    constexpr int K = 128;
    constexpr int ROWS = 16;
    constexpr int KCH = 16;
    constexpr int RLANES = 256 / OUT;   // 2 (OUT=128) or 4 (OUT=64)
    constexpr int RPT = ROWS / RLANES;  // 8 or 4 rows per thread

    __shared__ float hs[ROWS][K];       // 8 KB
    __shared__ float wls[KCH][OUT];     // 8/4 KB
    __shared__ float wrs[KCH][OUT];

    const int tid = threadIdx.x;
    const int base = blockIdx.x * ROWS;

    // stage h rows (float4)
    for (int i = tid; i < ROWS * K / 4; i += 256) {
        int r = i / (K / 4), c = i % (K / 4);
        float4 v = make_float4(0.f, 0.f, 0.f, 0.f);
        if (base + r < N) v = ((const float4*)(h + (size_t)(base + r) * K))[c];
        ((float4*)&hs[r][0])[c] = v;
    }

    const int j = tid % OUT;
    const int jr = tid / OUT;

    float accp[RPT], accq[RPT];
#pragma unroll
    for (int p = 0; p < RPT; ++p) { accp[p] = 0.f; accq[p] = 0.f; }

    for (int k0 = 0; k0 < K; k0 += KCH) {
        __syncthreads();
        for (int i = tid; i < KCH * OUT / 4; i += 256) {
            int kk = i / (OUT / 4), c = i % (OUT / 4);
            ((float4*)&wls[kk][0])[c] = ((const float4*)(Wl + (size_t)(k0 + kk) * OUT))[c];
            ((float4*)&wrs[kk][0])[c] = ((const float4*)(Wr + (size_t)(k0 + kk) * OUT))[c];
        }
        __syncthreads();
#pragma unroll
        for (int kk = 0; kk < KCH; kk += 4) {
            float wl0 = wls[kk + 0][j], wl1 = wls[kk + 1][j];
            float wl2 = wls[kk + 2][j], wl3 = wls[kk + 3][j];
            float wr0 = wrs[kk + 0][j], wr1 = wrs[kk + 1][j];
            float wr2 = wrs[kk + 2][j], wr3 = wrs[kk + 3][j];
#pragma unroll
            for (int p = 0; p < RPT; ++p) {
                const float4 hv = *(const float4*)&hs[jr + p * RLANES][k0 + kk];
                accp[p] = fmaf(hv.x, wl0, accp[p]); accq[p] = fmaf(hv.x, wr0, accq[p]);
                accp[p] = fmaf(hv.y, wl1, accp[p]); accq[p] = fmaf(hv.y, wr1, accq[p]);
                accp[p] = fmaf(hv.z, wl2, accp[p]); accq[p] = fmaf(hv.z, wr2, accq[p]);
                accp[p] = fmaf(hv.w, wl3, accp[p]); accq[p] = fmaf(hv.w, wr3, accq[p]);
            }
        }
    }

    const float bj = bias[j];
#pragma unroll
    for (int p = 0; p < RPT; ++p) {
        int r = base + jr + p * RLANES;
        if (r < N) {
            P[(size_t)r * OUT + j] = accp[p];
            Q[(size_t)r * OUT + j] = accq[p] + bj;
        }
    }
}

// ---- edge scatter: Q[dst] += P[src] * ideg[dst] ------------------------
template <int F>
__global__ void scatter_kernel(const int* __restrict__ src, const int* __restrict__ dst,
                               const float* __restrict__ P, const float* __restrict__ ideg,
                               float* __restrict__ Q, int E) {
    constexpr int C = F / 4;  // float4 chunks per row
    int t = blockIdx.x * blockDim.x + threadIdx.x;
    int e = t / C, c = t % C;
    if (e >= E) return;
    int s = src[e], d = dst[e];
    float4 v = ((const float4*)(P + (size_t)s * F))[c];
    float sc = ideg[d];
    float* q = Q + (size_t)d * F + (size_t)c * 4;
    unsafeAtomicAdd(q + 0, v.x * sc);
    unsafeAtomicAdd(q + 1, v.y * sc);
    unsafeAtomicAdd(q + 2, v.z * sc);
    unsafeAtomicAdd(q + 3, v.w * sc);
}

// ---- relu --------------------------------------------------------------
__global__ void relu_kernel(float4* __restrict__ Q, int n4) {
    int i = blockIdx.x * blockDim.x + threadIdx.x;
    if (i < n4) {
        float4 v = Q[i];
        v.x = fmaxf(v.x, 0.f); v.y = fmaxf(v.y, 0.f);
        v.z = fmaxf(v.z, 0.f); v.w = fmaxf(v.w, 0.f);
        Q[i] = v;
    }
}

// ---- global mean pool --------------------------------------------------
__global__ __launch_bounds__(256) void pool_kernel(const float* __restrict__ h,
                                                   const int* __restrict__ batch,
                                                   float* __restrict__ gsum,
                                                   float* __restrict__ gcnt, int N) {
    __shared__ float ls[NG * 64];  // 16 KB
    __shared__ float lc[NG];
    const int tid = threadIdx.x;
    for (int i = tid; i < NG * 64; i += 256) ls[i] = 0.f;
    if (tid < NG) lc[tid] = 0.f;
    __syncthreads();

    const int j = tid & 63;
    const int nl = tid >> 6;  // 4 node lanes
    const int base = blockIdx.x * 256;
    for (int i = nl; i < 256; i += 4) {
        int n = base + i;
        if (n < N) {
            int g = batch[n];
            atomicAdd(&ls[g * 64 + j], h[(size_t)n * 64 + j]);
            if (j == 0) atomicAdd(&lc[g], 1.f);
        }
    }
    __syncthreads();
    for (int i = tid; i < NG * 64; i += 256) {
        float v = ls[i];
        if (v != 0.f) unsafeAtomicAdd(&gsum[i], v);
    }
    if (tid < NG) {
        float c = lc[tid];
        if (c != 0.f) unsafeAtomicAdd(&gcnt[tid], c);
    }
}

__global__ void final_kernel(const float* __restrict__ gsum, const float* __restrict__ gcnt,
                             float* __restrict__ out) {
    int t = blockIdx.x * blockDim.x + threadIdx.x;
    if (t < NG * 64) out[t] = gsum[t] / fmaxf(gcnt[t >> 6], 1.0f);
}

// ---- launch ------------------------------------------------------------
extern "C" void kernel_launch(void* const* d_in, const int* in_sizes, int n_in,
                              void* d_out, int out_size, void* d_ws, size_t ws_size,
                              hipStream_t stream) {
    const float* x    = (const float*)d_in[0];
    const int*   ei   = (const int*)d_in[1];
    const int*   batch= (const int*)d_in[2];
    const float* Wl0  = (const float*)d_in[4];
    const float* Wr0  = (const float*)d_in[5];
    const float* b0   = (const float*)d_in[6];
    const float* Wl1  = (const float*)d_in[7];
    const float* Wr1  = (const float*)d_in[8];
    const float* b1   = (const float*)d_in[9];
    const float* Wl2  = (const float*)d_in[10];
    const float* Wr2  = (const float*)d_in[11];
    const float* b2   = (const float*)d_in[12];

    const int N = NN, E = NE;
    const int* src = ei;
    const int* dst = ei + E;

    const size_t BUF = (size_t)NN * 128 * sizeof(float);  // 51.2 MB
    char* ws = (char*)d_ws;
    float* bufA = (float*)(ws);
    float* bufB = (float*)(ws + BUF);
    float* bufP = (float*)(ws + 2 * BUF);
    float* ideg = (float*)(ws + 3 * BUF);
    float* gsum = (float*)(ws + 3 * BUF + (size_t)NN * sizeof(float));
    float* gcnt = gsum + NG * 64;

    hipMemsetAsync(ideg, 0, (size_t)N * sizeof(float), stream);
    hipMemsetAsync(gsum, 0, (size_t)(NG * 64 + NG) * sizeof(float), stream);

    deg_kernel<<<cdiv(E, 256), 256, 0, stream>>>(dst, ideg, E);
    ideg_kernel<<<cdiv(N, 256), 256, 0, stream>>>(ideg, N);

    // Layer 0: x -> bufA (Q), bufP (P); then scatter + relu
    sage_gemm<128><<<cdiv(N, 16), 256, 0, stream>>>(x, Wl0, Wr0, b0, bufP, bufA, N);
    scatter_kernel<128><<<cdiv(E * 32, 256), 256, 0, stream>>>(src, dst, bufP, ideg, bufA, E);
    relu_kernel<<<cdiv(N * 128 / 4, 256), 256, 0, stream>>>((float4*)bufA, N * 128 / 4);

    // Layer 1: bufA -> bufB
    sage_gemm<128><<<cdiv(N, 16), 256, 0, stream>>>(bufA, Wl1, Wr1, b1, bufP, bufB, N);
    scatter_kernel<128><<<cdiv(E * 32, 256), 256, 0, stream>>>(src, dst, bufP, ideg, bufB, E);
    relu_kernel<<<cdiv(N * 128 / 4, 256), 256, 0, stream>>>((float4*)bufB, N * 128 / 4);

    // Layer 2 (OUT=64, no relu): bufB -> bufA (compact N x 64)
    sage_gemm<64><<<cdiv(N, 16), 256, 0, stream>>>(bufB, Wl2, Wr2, b2, bufP, bufA, N);
    scatter_kernel<64><<<cdiv(E * 16, 256), 256, 0, stream>>>(src, dst, bufP, ideg, bufA, E);

    // Pool
    pool_kernel<<<cdiv(N, 256), 256, 0, stream>>>(bufA, batch, gsum, gcnt, N);
    final_kernel<<<16, 256, 0, stream>>>(gsum, gcnt, (float*)d_out);
}

// Round 2
// 926.473 us; speedup vs baseline: 7.8572x; 7.8572x over previous
//
#include <hip/hip_runtime.h>

#define NN 100000
#define NE 1600000
#define NG 64

static inline int cdiv(int a, int b) { return (a + b - 1) / b; }

// ---- degree (float atomic; fallback path) ------------------------------
__global__ void deg_kernel(const int* __restrict__ dst, float* __restrict__ deg, int E) {
    int e = blockIdx.x * blockDim.x + threadIdx.x;
    if (e < E) unsafeAtomicAdd(&deg[dst[e]], 1.0f);
}

__global__ void ideg_kernel(float* __restrict__ deg, int N) {
    int n = blockIdx.x * blockDim.x + threadIdx.x;
    if (n < N) deg[n] = 1.0f / fmaxf(deg[n], 1.0f);
}

// ---- CSR build ---------------------------------------------------------
__global__ void deg_int_kernel(const int* __restrict__ dst, int* __restrict__ deg, int E) {
    int e = blockIdx.x * blockDim.x + threadIdx.x;
    if (e < E) atomicAdd(&deg[dst[e]], 1);
}

// per-block exclusive scan over 256 elements; block total to bsum
__global__ void scan1_kernel(const int* __restrict__ deg, int* __restrict__ off,
                             int* __restrict__ bsum, int N) {
    __shared__ int s[256];
    int t = threadIdx.x, idx = blockIdx.x * 256 + t;
    int v = (idx < N) ? deg[idx] : 0;
    s[t] = v;
    __syncthreads();
    for (int o = 1; o < 256; o <<= 1) {
        int u = (t >= o) ? s[t - o] : 0;
        __syncthreads();
        s[t] += u;
        __syncthreads();
    }
    if (idx < N) off[idx] = s[t] - v;
    if (t == 255) bsum[blockIdx.x] = s[255];
}

// single-block exclusive scan over up to 512 block sums
__global__ void scan2_kernel(int* __restrict__ bsum, int NB) {
    __shared__ int s[512];
    int t = threadIdx.x;
    int v = (t < NB) ? bsum[t] : 0;
    s[t] = v;
    __syncthreads();
    for (int o = 1; o < 512; o <<= 1) {
        int u = (t >= o) ? s[t - o] : 0;
        __syncthreads();
        s[t] += u;
        __syncthreads();
    }
    if (t < NB) bsum[t] = s[t] - v;
}

__global__ void scan3_kernel(int* __restrict__ off, const int* __restrict__ bsum, int N, int E) {
    int idx = blockIdx.x * 256 + threadIdx.x;
    if (idx < N) off[idx] += bsum[blockIdx.x];
    if (idx == 0) off[N] = E;
}

__global__ void ideg_from_off_kernel(const int* __restrict__ off, float* __restrict__ ideg, int N) {
    int n = blockIdx.x * blockDim.x + threadIdx.x;
    if (n < N) ideg[n] = 1.0f / (float)max(off[n + 1] - off[n], 1);
}

__global__ void fill_kernel(const int* __restrict__ src, const int* __restrict__ dst,
                            const int* __restrict__ off, int* __restrict__ cursor,
                            int* __restrict__ csr, int E) {
    int e = blockIdx.x * blockDim.x + threadIdx.x;
    if (e >= E) return;
    int d = dst[e];
    int pos = off[d] + atomicAdd(&cursor[d], 1);
    csr[pos] = src[e];
}

// ---- fused dual GEMM: P = h@Wl, Q = h@Wr + b ---------------------------
template <int OUT>
__global__ __launch_bounds__(256) void sage_gemm(
    const float* __restrict__ h, const float* __restrict__ Wl,
    const float* __restrict__ Wr, const float* __restrict__ bias,
    float* __restrict__ P, float* __restrict__ Q, int N) {
    constexpr int K = 128;
    constexpr int ROWS = 16;
    constexpr int KCH = 16;
    constexpr int RLANES = 256 / OUT;
    constexpr int RPT = ROWS / RLANES;

    __shared__ float hs[ROWS][K];
    __shared__ float wls[KCH][OUT];
    __shared__ float wrs[KCH][OUT];

    const int tid = threadIdx.x;
    const int base = blockIdx.x * ROWS;

    for (int i = tid; i < ROWS * K / 4; i += 256) {
        int r = i / (K / 4), c = i % (K / 4);
        float4 v = make_float4(0.f, 0.f, 0.f, 0.f);
        if (base + r < N) v = ((const float4*)(h + (size_t)(base + r) * K))[c];
        ((float4*)&hs[r][0])[c] = v;
    }

    const int j = tid % OUT;
    const int jr = tid / OUT;

    float accp[RPT], accq[RPT];
#pragma unroll
    for (int p = 0; p < RPT; ++p) { accp[p] = 0.f; accq[p] = 0.f; }

    for (int k0 = 0; k0 < K; k0 += KCH) {
        __syncthreads();
        for (int i = tid; i < KCH * OUT / 4; i += 256) {
            int kk = i / (OUT / 4), c = i % (OUT / 4);
            ((float4*)&wls[kk][0])[c] = ((const float4*)(Wl + (size_t)(k0 + kk) * OUT))[c];
            ((float4*)&wrs[kk][0])[c] = ((const float4*)(Wr + (size_t)(k0 + kk) * OUT))[c];
        }
        __syncthreads();
#pragma unroll
        for (int kk = 0; kk < KCH; kk += 4) {
            float wl0 = wls[kk + 0][j], wl1 = wls[kk + 1][j];
            float wl2 = wls[kk + 2][j], wl3 = wls[kk + 3][j];
            float wr0 = wrs[kk + 0][j], wr1 = wrs[kk + 1][j];
            float wr2 = wrs[kk + 2][j], wr3 = wrs[kk + 3][j];
#pragma unroll
            for (int p = 0; p < RPT; ++p) {
                const float4 hv = *(const float4*)&hs[jr + p * RLANES][k0 + kk];
                accp[p] = fmaf(hv.x, wl0, accp[p]); accq[p] = fmaf(hv.x, wr0, accq[p]);
                accp[p] = fmaf(hv.y, wl1, accp[p]); accq[p] = fmaf(hv.y, wr1, accq[p]);
                accp[p] = fmaf(hv.z, wl2, accp[p]); accq[p] = fmaf(hv.z, wr2, accq[p]);
                accp[p] = fmaf(hv.w, wl3, accp[p]); accq[p] = fmaf(hv.w, wr3, accq[p]);
            }
        }
    }

    const float bj = bias[j];
#pragma unroll
    for (int p = 0; p < RPT; ++p) {
        int r = base + jr + p * RLANES;
        if (r < N) {
            P[(size_t)r * OUT + j] = accp[p];
            Q[(size_t)r * OUT + j] = accq[p] + bj;
        }
    }
}

// ---- CSR gather: Q[n] = relu?(Q[n] + ideg[n] * sum_{e in in(n)} P[src_e])
template <int F, bool RELU>
__global__ __launch_bounds__(256) void gather_kernel(
    const int* __restrict__ csr, const int* __restrict__ off,
    const float* __restrict__ P, const float* __restrict__ ideg,
    float* __restrict__ Q, int N) {
    constexpr int C = F / 4;  // threads per node row
    int t = blockIdx.x * blockDim.x + threadIdx.x;
    int n = t / C, c = t % C;
    if (n >= N) return;
    int e0 = off[n], e1 = off[n + 1];

    float4 acc = make_float4(0.f, 0.f, 0.f, 0.f);
    int e = e0;
    for (; e + 4 <= e1; e += 4) {
        int s0 = csr[e + 0], s1 = csr[e + 1], s2 = csr[e + 2], s3 = csr[e + 3];
        float4 v0 = ((const float4*)(P + (size_t)s0 * F))[c];
        float4 v1 = ((const float4*)(P + (size_t)s1 * F))[c];
        float4 v2 = ((const float4*)(P + (size_t)s2 * F))[c];
        float4 v3 = ((const float4*)(P + (size_t)s3 * F))[c];
        acc.x += (v0.x + v1.x) + (v2.x + v3.x);
        acc.y += (v0.y + v1.y) + (v2.y + v3.y);
        acc.z += (v0.z + v1.z) + (v2.z + v3.z);
        acc.w += (v0.w + v1.w) + (v2.w + v3.w);
    }
    for (; e < e1; ++e) {
        int s = csr[e];
        float4 v = ((const float4*)(P + (size_t)s * F))[c];
        acc.x += v.x; acc.y += v.y; acc.z += v.z; acc.w += v.w;
    }

    float sc = ideg[n];
    float4 q = ((const float4*)(Q + (size_t)n * F))[c];
    q.x = fmaf(acc.x, sc, q.x);
    q.y = fmaf(acc.y, sc, q.y);
    q.z = fmaf(acc.z, sc, q.z);
    q.w = fmaf(acc.w, sc, q.w);
    if (RELU) {
        q.x = fmaxf(q.x, 0.f); q.y = fmaxf(q.y, 0.f);
        q.z = fmaxf(q.z, 0.f); q.w = fmaxf(q.w, 0.f);
    }
    ((float4*)(Q + (size_t)n * F))[c] = q;
}

// ---- fallback edge scatter (atomics) -----------------------------------
template <int F>
__global__ void scatter_kernel(const int* __restrict__ src, const int* __restrict__ dst,
                               const float* __restrict__ P, const float* __restrict__ ideg,
                               float* __restrict__ Q, int E) {
    constexpr int C = F / 4;
    int t = blockIdx.x * blockDim.x + threadIdx.x;
    int e = t / C, c = t % C;
    if (e >= E) return;
    int s = src[e], d = dst[e];
    float4 v = ((const float4*)(P + (size_t)s * F))[c];
    float sc = ideg[d];
    float* q = Q + (size_t)d * F + (size_t)c * 4;
    unsafeAtomicAdd(q + 0, v.x * sc);
    unsafeAtomicAdd(q + 1, v.y * sc);
    unsafeAtomicAdd(q + 2, v.z * sc);
    unsafeAtomicAdd(q + 3, v.w * sc);
}

__global__ void relu_kernel(float4* __restrict__ Q, int n4) {
    int i = blockIdx.x * blockDim.x + threadIdx.x;
    if (i < n4) {
        float4 v = Q[i];
        v.x = fmaxf(v.x, 0.f); v.y = fmaxf(v.y, 0.f);
        v.z = fmaxf(v.z, 0.f); v.w = fmaxf(v.w, 0.f);
        Q[i] = v;
    }
}

// ---- global mean pool --------------------------------------------------
__global__ __launch_bounds__(256) void pool_kernel(const float* __restrict__ h,
                                                   const int* __restrict__ batch,
                                                   float* __restrict__ gsum,
                                                   float* __restrict__ gcnt, int N) {
    __shared__ float ls[NG * 64];
    __shared__ float lc[NG];
    const int tid = threadIdx.x;
    for (int i = tid; i < NG * 64; i += 256) ls[i] = 0.f;
    if (tid < NG) lc[tid] = 0.f;
    __syncthreads();

    const int j = tid & 63;
    const int nl = tid >> 6;
    const int base = blockIdx.x * 256;
    for (int i = nl; i < 256; i += 4) {
        int n = base + i;
        if (n < N) {
            int g = batch[n];
            atomicAdd(&ls[g * 64 + j], h[(size_t)n * 64 + j]);
            if (j == 0) atomicAdd(&lc[g], 1.f);
        }
    }
    __syncthreads();
    for (int i = tid; i < NG * 64; i += 256) {
        float v = ls[i];
        if (v != 0.f) unsafeAtomicAdd(&gsum[i], v);
    }
    if (tid < NG) {
        float c = lc[tid];
        if (c != 0.f) unsafeAtomicAdd(&gcnt[tid], c);
    }
}

__global__ void final_kernel(const float* __restrict__ gsum, const float* __restrict__ gcnt,
                             float* __restrict__ out) {
    int t = blockIdx.x * blockDim.x + threadIdx.x;
    if (t < NG * 64) out[t] = gsum[t] / fmaxf(gcnt[t >> 6], 1.0f);
}

// ---- launch ------------------------------------------------------------
extern "C" void kernel_launch(void* const* d_in, const int* in_sizes, int n_in,
                              void* d_out, int out_size, void* d_ws, size_t ws_size,
                              hipStream_t stream) {
    const float* x     = (const float*)d_in[0];
    const int*   ei    = (const int*)d_in[1];
    const int*   batch = (const int*)d_in[2];
    const float* Wl0 = (const float*)d_in[4];
    const float* Wr0 = (const float*)d_in[5];
    const float* b0  = (const float*)d_in[6];
    const float* Wl1 = (const float*)d_in[7];
    const float* Wr1 = (const float*)d_in[8];
    const float* b1  = (const float*)d_in[9];
    const float* Wl2 = (const float*)d_in[10];
    const float* Wr2 = (const float*)d_in[11];
    const float* b2  = (const float*)d_in[12];

    const int N = NN, E = NE;
    const int* src = ei;
    const int* dst = ei + E;

    const size_t BUF = (size_t)NN * 128 * sizeof(float);  // 51.2 MB
    char* ws = (char*)d_ws;
    float* bufA = (float*)(ws);             // Q0 / Q2
    float* bufB = (float*)(ws + BUF);       // Q1
    float* bufP = (float*)(ws + 2 * BUF);   // P
    char* p = ws + 3 * BUF;
    float* ideg = (float*)p;        p += (size_t)N * 4;
    int* off    = (int*)p;          p += (size_t)(N + 1) * 4;
    int* cursor = (int*)p;          p += (size_t)N * 4;
    int* bsum   = (int*)p;          p += 2048;
    float* gsum = (float*)p;        p += (size_t)NG * 64 * 4;
    float* gcnt = (float*)p;        p += (size_t)NG * 4;
    int* csr    = (int*)p;          p += (size_t)E * 4;
    const size_t needed = (size_t)(p - ws);

    hipMemsetAsync(gsum, 0, (size_t)(NG * 64 + NG) * sizeof(float), stream);

    const int NB = cdiv(N, 256);  // 391

    if (ws_size >= needed) {
        // ---- CSR path ----
        hipMemsetAsync(cursor, 0, (size_t)N * sizeof(int), stream);
        deg_int_kernel<<<cdiv(E, 256), 256, 0, stream>>>(dst, cursor, E);
        scan1_kernel<<<NB, 256, 0, stream>>>(cursor, off, bsum, N);
        scan2_kernel<<<1, 512, 0, stream>>>(bsum, NB);
        scan3_kernel<<<NB, 256, 0, stream>>>(off, bsum, N, E);
        ideg_from_off_kernel<<<cdiv(N, 256), 256, 0, stream>>>(off, ideg, N);
        hipMemsetAsync(cursor, 0, (size_t)N * sizeof(int), stream);
        fill_kernel<<<cdiv(E, 256), 256, 0, stream>>>(src, dst, off, cursor, csr, E);

        sage_gemm<128><<<cdiv(N, 16), 256, 0, stream>>>(x, Wl0, Wr0, b0, bufP, bufA, N);
        gather_kernel<128, true><<<cdiv(N * 32, 256), 256, 0, stream>>>(csr, off, bufP, ideg, bufA, N);

        sage_gemm<128><<<cdiv(N, 16), 256, 0, stream>>>(bufA, Wl1, Wr1, b1, bufP, bufB, N);
        gather_kernel<128, true><<<cdiv(N * 32, 256), 256, 0, stream>>>(csr, off, bufP, ideg, bufB, N);

        sage_gemm<64><<<cdiv(N, 16), 256, 0, stream>>>(bufB, Wl2, Wr2, b2, bufP, bufA, N);
        gather_kernel<64, false><<<cdiv(N * 16, 256), 256, 0, stream>>>(csr, off, bufP, ideg, bufA, N);
    } else {
        // ---- fallback: atomic scatter path ----
        hipMemsetAsync(ideg, 0, (size_t)N * sizeof(float), stream);
        deg_kernel<<<cdiv(E, 256), 256, 0, stream>>>(dst, ideg, E);
        ideg_kernel<<<cdiv(N, 256), 256, 0, stream>>>(ideg, N);

        sage_gemm<128><<<cdiv(N, 16), 256, 0, stream>>>(x, Wl0, Wr0, b0, bufP, bufA, N);
        scatter_kernel<128><<<cdiv(E * 32, 256), 256, 0, stream>>>(src, dst, bufP, ideg, bufA, E);
        relu_kernel<<<cdiv(N * 128 / 4, 256), 256, 0, stream>>>((float4*)bufA, N * 128 / 4);

        sage_gemm<128><<<cdiv(N, 16), 256, 0, stream>>>(bufA, Wl1, Wr1, b1, bufP, bufB, N);
        scatter_kernel<128><<<cdiv(E * 32, 256), 256, 0, stream>>>(src, dst, bufP, ideg, bufB, E);
        relu_kernel<<<cdiv(N * 128 / 4, 256), 256, 0, stream>>>((float4*)bufB, N * 128 / 4);

        sage_gemm<64><<<cdiv(N, 16), 256, 0, stream>>>(bufB, Wl2, Wr2, b2, bufP, bufA, N);
        scatter_kernel<64><<<cdiv(E * 16, 256), 256, 0, stream>>>(src, dst, bufP, ideg, bufA, E);
    }

    pool_kernel<<<cdiv(N, 256), 256, 0, stream>>>(bufA, batch, gsum, gcnt, N);
    final_kernel<<<16, 256, 0, stream>>>(gsum, gcnt, (float*)d_out);
}

// Round 3
// 570.906 us; speedup vs baseline: 12.7507x; 1.6228x over previous
//
#include <hip/hip_runtime.h>
#include <hip/hip_bf16.h>

#define NN 100000
#define NE 1600000
#define NG 64

typedef short short8 __attribute__((ext_vector_type(8)));
typedef float f32x4 __attribute__((ext_vector_type(4)));
typedef unsigned short ushort4v __attribute__((ext_vector_type(4)));

static inline int cdiv(int a, int b) { return (a + b - 1) / b; }

__device__ __forceinline__ short f2bf(float f) {
    return __builtin_bit_cast(short, __float2bfloat16(f));
}
__device__ __forceinline__ float bf2f(unsigned short u) {
    unsigned int x = ((unsigned int)u) << 16;
    return __builtin_bit_cast(float, x);
}

// ---- CSR build ---------------------------------------------------------
__global__ void deg_int_kernel(const int* __restrict__ dst, int* __restrict__ deg, int E) {
    int e = blockIdx.x * blockDim.x + threadIdx.x;
    if (e < E) atomicAdd(&deg[dst[e]], 1);
}

__global__ void scan1_kernel(const int* __restrict__ deg, int* __restrict__ off,
                             int* __restrict__ bsum, int N) {
    __shared__ int s[256];
    int t = threadIdx.x, idx = blockIdx.x * 256 + t;
    int v = (idx < N) ? deg[idx] : 0;
    s[t] = v;
    __syncthreads();
    for (int o = 1; o < 256; o <<= 1) {
        int u = (t >= o) ? s[t - o] : 0;
        __syncthreads();
        s[t] += u;
        __syncthreads();
    }
    if (idx < N) off[idx] = s[t] - v;
    if (t == 255) bsum[blockIdx.x] = s[255];
}

__global__ void scan2_kernel(int* __restrict__ bsum, int NB) {
    __shared__ int s[512];
    int t = threadIdx.x;
    int v = (t < NB) ? bsum[t] : 0;
    s[t] = v;
    __syncthreads();
    for (int o = 1; o < 512; o <<= 1) {
        int u = (t >= o) ? s[t - o] : 0;
        __syncthreads();
        s[t] += u;
        __syncthreads();
    }
    if (t < NB) bsum[t] = s[t] - v;
}

__global__ void scan3_kernel(int* __restrict__ off, const int* __restrict__ bsum, int N, int E) {
    int idx = blockIdx.x * 256 + threadIdx.x;
    if (idx < N) off[idx] += bsum[blockIdx.x];
    if (idx == 0) off[N] = E;
}

__global__ void ideg_from_off_kernel(const int* __restrict__ off, float* __restrict__ ideg, int N) {
    int n = blockIdx.x * blockDim.x + threadIdx.x;
    if (n < N) ideg[n] = 1.0f / (float)max(off[n + 1] - off[n], 1);
}

__global__ void fill_kernel(const int* __restrict__ src, const int* __restrict__ dst,
                            const int* __restrict__ off, int* __restrict__ cursor,
                            int* __restrict__ csr, int E) {
    int e = blockIdx.x * blockDim.x + threadIdx.x;
    if (e >= E) return;
    int d = dst[e];
    int pos = off[d] + atomicAdd(&cursor[d], 1);
    csr[pos] = src[e];
}

// ---- weight transpose+convert: WT[c][k] bf16, c in [0,2*OUT) -----------
template <int OUT>
__global__ void wt_kernel(const float* __restrict__ Wl, const float* __restrict__ Wr,
                          short* __restrict__ WT) {
    int idx = blockIdx.x * 256 + threadIdx.x;
    if (idx >= 2 * OUT * 128) return;
    int c = idx >> 7, k = idx & 127;
    float v = (c < OUT) ? Wl[k * OUT + c] : Wr[k * OUT + (c - OUT)];
    WT[idx] = f2bf(v);
}

// ---- MFMA dual GEMM: P(bf16) = h@Wl, Q(f32) = h@Wr + b -----------------
// h: [N][128] f32. WT: [2*OUT][128] bf16. Block: 4 waves, 64 rows.
// Waves 0,1 -> P cols [0,OUT); waves 2,3 -> Q cols [0,OUT).
template <int OUT>
__global__ __launch_bounds__(256) void sage_gemm_mfma(
    const float* __restrict__ h, const short* __restrict__ WT,
    const float* __restrict__ bias,
    short* __restrict__ P, float* __restrict__ Q, int N) {
    constexpr int K = 128;
    constexpr int NT = OUT / 32;  // n-tiles of 16 per wave

    const int tid = threadIdx.x;
    const int w = tid >> 6;
    const int lane = tid & 63;
    const int l15 = lane & 15;
    const int lhi = lane >> 4;  // 0..3
    const int rowBase = blockIdx.x * 64;
    const int colBase = w * (OUT / 2);
    const bool isQ = (w >= 2);
    const int qcolBase = colBase - OUT;

    f32x4 acc[4][NT];
#pragma unroll
    for (int mt = 0; mt < 4; ++mt)
#pragma unroll
        for (int nt = 0; nt < NT; ++nt) acc[mt][nt] = (f32x4){0.f, 0.f, 0.f, 0.f};

#pragma unroll
    for (int kt = 0; kt < 4; ++kt) {
        const int k0 = kt * 32 + lhi * 8;
        short8 a[4], b[NT];
#pragma unroll
        for (int mt = 0; mt < 4; ++mt) {
            int r = rowBase + mt * 16 + l15;
            r = min(r, N - 1);
            const float* hp = h + (size_t)r * K + k0;
            float4 v0 = *(const float4*)hp;
            float4 v1 = *(const float4*)(hp + 4);
            a[mt][0] = f2bf(v0.x); a[mt][1] = f2bf(v0.y);
            a[mt][2] = f2bf(v0.z); a[mt][3] = f2bf(v0.w);
            a[mt][4] = f2bf(v1.x); a[mt][5] = f2bf(v1.y);
            a[mt][6] = f2bf(v1.z); a[mt][7] = f2bf(v1.w);
        }
#pragma unroll
        for (int nt = 0; nt < NT; ++nt)
            b[nt] = *(const short8*)(WT + (size_t)(colBase + nt * 16 + l15) * K + k0);
#pragma unroll
        for (int mt = 0; mt < 4; ++mt)
#pragma unroll
            for (int nt = 0; nt < NT; ++nt)
                acc[mt][nt] = __builtin_amdgcn_mfma_f32_16x16x32_bf16(a[mt], b[nt], acc[mt][nt], 0, 0, 0);
    }

    if (!isQ) {
#pragma unroll
        for (int mt = 0; mt < 4; ++mt) {
#pragma unroll
            for (int nt = 0; nt < NT; ++nt) {
                int col = colBase + nt * 16 + l15;
#pragma unroll
                for (int rg = 0; rg < 4; ++rg) {
                    int row = rowBase + mt * 16 + lhi * 4 + rg;
                    if (row < N) P[(size_t)row * OUT + col] = f2bf(acc[mt][nt][rg]);
                }
            }
        }
    } else {
        float bj[NT];
#pragma unroll
        for (int nt = 0; nt < NT; ++nt) bj[nt] = bias[qcolBase + nt * 16 + l15];
#pragma unroll
        for (int mt = 0; mt < 4; ++mt) {
#pragma unroll
            for (int nt = 0; nt < NT; ++nt) {
                int col = qcolBase + nt * 16 + l15;
#pragma unroll
                for (int rg = 0; rg < 4; ++rg) {
                    int row = rowBase + mt * 16 + lhi * 4 + rg;
                    if (row < N) Q[(size_t)row * OUT + col] = acc[mt][nt][rg] + bj[nt];
                }
            }
        }
    }
}

// ---- CSR gather: Q[n] = relu?(Q[n] + ideg[n] * sum P[src]) -------------
template <int F, bool RELU>
__global__ __launch_bounds__(256) void gather_kernel(
    const int* __restrict__ csr, const int* __restrict__ off,
    const short* __restrict__ P, const float* __restrict__ ideg,
    float* __restrict__ Q, int N) {
    constexpr int C = F / 4;  // threads per node row
    int t = blockIdx.x * blockDim.x + threadIdx.x;
    int n = t / C, c = t % C;
    if (n >= N) return;
    int e0 = off[n], e1 = off[n + 1];

    float ax = 0.f, ay = 0.f, az = 0.f, aw = 0.f;
    int e = e0;
    for (; e + 4 <= e1; e += 4) {
        int s0 = csr[e + 0], s1 = csr[e + 1], s2 = csr[e + 2], s3 = csr[e + 3];
        ushort4v u0 = *(const ushort4v*)(P + (size_t)s0 * F + c * 4);
        ushort4v u1 = *(const ushort4v*)(P + (size_t)s1 * F + c * 4);
        ushort4v u2 = *(const ushort4v*)(P + (size_t)s2 * F + c * 4);
        ushort4v u3 = *(const ushort4v*)(P + (size_t)s3 * F + c * 4);
        ax += (bf2f(u0[0]) + bf2f(u1[0])) + (bf2f(u2[0]) + bf2f(u3[0]));
        ay += (bf2f(u0[1]) + bf2f(u1[1])) + (bf2f(u2[1]) + bf2f(u3[1]));
        az += (bf2f(u0[2]) + bf2f(u1[2])) + (bf2f(u2[2]) + bf2f(u3[2]));
        aw += (bf2f(u0[3]) + bf2f(u1[3])) + (bf2f(u2[3]) + bf2f(u3[3]));
    }
    for (; e < e1; ++e) {
        int s = csr[e];
        ushort4v u = *(const ushort4v*)(P + (size_t)s * F + c * 4);
        ax += bf2f(u[0]); ay += bf2f(u[1]); az += bf2f(u[2]); aw += bf2f(u[3]);
    }

    float sc = ideg[n];
    float4 q = ((const float4*)(Q + (size_t)n * F))[c];
    q.x = fmaf(ax, sc, q.x);
    q.y = fmaf(ay, sc, q.y);
    q.z = fmaf(az, sc, q.z);
    q.w = fmaf(aw, sc, q.w);
    if (RELU) {
        q.x = fmaxf(q.x, 0.f); q.y = fmaxf(q.y, 0.f);
        q.z = fmaxf(q.z, 0.f); q.w = fmaxf(q.w, 0.f);
    }
    ((float4*)(Q + (size_t)n * F))[c] = q;
}

// ---- global mean pool --------------------------------------------------
__global__ __launch_bounds__(256) void pool_kernel(const float* __restrict__ h,
                                                   const int* __restrict__ batch,
                                                   float* __restrict__ gsum,
                                                   float* __restrict__ gcnt, int N) {
    __shared__ float ls[NG * 64];
    __shared__ float lc[NG];
    const int tid = threadIdx.x;
    for (int i = tid; i < NG * 64; i += 256) ls[i] = 0.f;
    if (tid < NG) lc[tid] = 0.f;
    __syncthreads();

    const int j = tid & 63;
    const int nl = tid >> 6;
    const int base = blockIdx.x * 256;
    for (int i = nl; i < 256; i += 4) {
        int n = base + i;
        if (n < N) {
            int g = batch[n];
            atomicAdd(&ls[g * 64 + j], h[(size_t)n * 64 + j]);
            if (j == 0) atomicAdd(&lc[g], 1.f);
        }
    }
    __syncthreads();
    for (int i = tid; i < NG * 64; i += 256) {
        float v = ls[i];
        if (v != 0.f) unsafeAtomicAdd(&gsum[i], v);
    }
    if (tid < NG) {
        float c = lc[tid];
        if (c != 0.f) unsafeAtomicAdd(&gcnt[tid], c);
    }
}

__global__ void final_kernel(const float* __restrict__ gsum, const float* __restrict__ gcnt,
                             float* __restrict__ out) {
    int t = blockIdx.x * blockDim.x + threadIdx.x;
    if (t < NG * 64) out[t] = gsum[t] / fmaxf(gcnt[t >> 6], 1.0f);
}

// ---- launch ------------------------------------------------------------
extern "C" void kernel_launch(void* const* d_in, const int* in_sizes, int n_in,
                              void* d_out, int out_size, void* d_ws, size_t ws_size,
                              hipStream_t stream) {
    const float* x     = (const float*)d_in[0];
    const int*   ei    = (const int*)d_in[1];
    const int*   batch = (const int*)d_in[2];
    const float* Wl0 = (const float*)d_in[4];
    const float* Wr0 = (const float*)d_in[5];
    const float* b0  = (const float*)d_in[6];
    const float* Wl1 = (const float*)d_in[7];
    const float* Wr1 = (const float*)d_in[8];
    const float* b1  = (const float*)d_in[9];
    const float* Wl2 = (const float*)d_in[10];
    const float* Wr2 = (const float*)d_in[11];
    const float* b2  = (const float*)d_in[12];

    const int N = NN, E = NE;
    const int* src = ei;
    const int* dst = ei + E;

    const size_t BUF = (size_t)NN * 128 * sizeof(float);  // 51.2 MB
    char* ws = (char*)d_ws;
    float* bufA = (float*)(ws);                  // h (f32), layer outputs
    float* bufB = (float*)(ws + BUF);
    short* bufP = (short*)(ws + 2 * BUF);        // P, bf16 [N][128] max
    char* p = ws + 2 * BUF + (size_t)NN * 128 * 2;
    short* WT0  = (short*)p;        p += 256 * 128 * 2;
    short* WT1  = (short*)p;        p += 256 * 128 * 2;
    short* WT2  = (short*)p;        p += 128 * 128 * 2;
    float* ideg = (float*)p;        p += (size_t)N * 4;
    int* off    = (int*)p;          p += (size_t)(N + 1) * 4 + 4;
    int* cursor = (int*)p;          p += (size_t)N * 4;
    int* bsum   = (int*)p;          p += 2048;
    float* gsum = (float*)p;        p += (size_t)NG * 64 * 4;
    float* gcnt = (float*)p;        p += (size_t)NG * 4;
    int* csr    = (int*)p;          p += (size_t)E * 4;

    const int NB = cdiv(N, 256);  // 391

    hipMemsetAsync(gsum, 0, (size_t)(NG * 64 + NG) * sizeof(float), stream);

    // CSR build
    hipMemsetAsync(cursor, 0, (size_t)N * sizeof(int), stream);
    deg_int_kernel<<<cdiv(E, 256), 256, 0, stream>>>(dst, cursor, E);
    scan1_kernel<<<NB, 256, 0, stream>>>(cursor, off, bsum, N);
    scan2_kernel<<<1, 512, 0, stream>>>(bsum, NB);
    scan3_kernel<<<NB, 256, 0, stream>>>(off, bsum, N, E);
    ideg_from_off_kernel<<<cdiv(N, 256), 256, 0, stream>>>(off, ideg, N);
    hipMemsetAsync(cursor, 0, (size_t)N * sizeof(int), stream);
    fill_kernel<<<cdiv(E, 256), 256, 0, stream>>>(src, dst, off, cursor, csr, E);

    // weights -> bf16 transposed
    wt_kernel<128><<<cdiv(2 * 128 * 128, 256), 256, 0, stream>>>(Wl0, Wr0, WT0);
    wt_kernel<128><<<cdiv(2 * 128 * 128, 256), 256, 0, stream>>>(Wl1, Wr1, WT1);
    wt_kernel<64><<<cdiv(2 * 64 * 128, 256), 256, 0, stream>>>(Wl2, Wr2, WT2);

    const int GB = cdiv(N, 64);  // gemm blocks

    // Layer 0
    sage_gemm_mfma<128><<<GB, 256, 0, stream>>>(x, WT0, b0, bufP, bufA, N);
    gather_kernel<128, true><<<cdiv(N * 32, 256), 256, 0, stream>>>(csr, off, bufP, ideg, bufA, N);
    // Layer 1
    sage_gemm_mfma<128><<<GB, 256, 0, stream>>>(bufA, WT1, b1, bufP, bufB, N);
    gather_kernel<128, true><<<cdiv(N * 32, 256), 256, 0, stream>>>(csr, off, bufP, ideg, bufB, N);
    // Layer 2 (no relu)
    sage_gemm_mfma<64><<<GB, 256, 0, stream>>>(bufB, WT2, b2, bufP, bufA, N);
    gather_kernel<64, false><<<cdiv(N * 16, 256), 256, 0, stream>>>(csr, off, bufP, ideg, bufA, N);

    // Pool
    pool_kernel<<<cdiv(N, 256), 256, 0, stream>>>(bufA, batch, gsum, gcnt, N);
    final_kernel<<<16, 256, 0, stream>>>(gsum, gcnt, (float*)d_out);
}

// Round 4
// 449.791 us; speedup vs baseline: 16.1841x; 1.2693x over previous
//
#include <hip/hip_runtime.h>
#include <hip/hip_bf16.h>

#define NN 100000
#define NE 1600000
#define NG 64
#define NBUK 782   // cdiv(NN,128)
#define ABLK 98    // binning blocks
#define ACH 16384  // edges per binning block

typedef short short8 __attribute__((ext_vector_type(8)));
typedef float f32x4 __attribute__((ext_vector_type(4)));
typedef unsigned short ushort4v __attribute__((ext_vector_type(4)));

static inline int cdiv(int a, int b) { return (a + b - 1) / b; }

__device__ __forceinline__ short f2bf(float f) {
    return __builtin_bit_cast(short, __float2bfloat16(f));
}
__device__ __forceinline__ float bf2f(unsigned short u) {
    unsigned int x = ((unsigned int)u) << 16;
    return __builtin_bit_cast(float, x);
}

// ---- bucketed CSR build (no global atomics) ----------------------------
__global__ __launch_bounds__(256) void histA_kernel(const int* __restrict__ dst,
                                                    int* __restrict__ blockHist, int E) {
    __shared__ int h[NBUK];
    for (int i = threadIdx.x; i < NBUK; i += 256) h[i] = 0;
    __syncthreads();
    int base = blockIdx.x * ACH;
    int end = min(base + ACH, E);
    for (int e = base + threadIdx.x; e < end; e += 256) atomicAdd(&h[dst[e] >> 7], 1);
    __syncthreads();
    for (int i = threadIdx.x; i < NBUK; i += 256) blockHist[(size_t)i * ABLK + blockIdx.x] = h[i];
}

// per bucket: exclusive scan of its ABLK block-counts; total -> bucketTot
__global__ __launch_bounds__(128) void scanBlk_kernel(int* __restrict__ blockHist,
                                                      int* __restrict__ bucketTot) {
    __shared__ int s[128];
    int b = blockIdx.x, t = threadIdx.x;
    int v = (t < ABLK) ? blockHist[(size_t)b * ABLK + t] : 0;
    s[t] = v;
    __syncthreads();
    for (int o = 1; o < 128; o <<= 1) {
        int u = (t >= o) ? s[t - o] : 0;
        __syncthreads();
        s[t] += u;
        __syncthreads();
    }
    if (t < ABLK) blockHist[(size_t)b * ABLK + t] = s[t] - v;
    if (t == 127) bucketTot[b] = s[127];
}

// single block: exclusive scan of bucket totals -> bucketBase
__global__ __launch_bounds__(1024) void scanTot_kernel(const int* __restrict__ bucketTot,
                                                       int* __restrict__ bucketBase,
                                                       int* __restrict__ off, int E) {
    __shared__ int s[1024];
    int t = threadIdx.x;
    int v = (t < NBUK) ? bucketTot[t] : 0;
    s[t] = v;
    __syncthreads();
    for (int o = 1; o < 1024; o <<= 1) {
        int u = (t >= o) ? s[t - o] : 0;
        __syncthreads();
        s[t] += u;
        __syncthreads();
    }
    if (t < NBUK) bucketBase[t] = s[t] - v;
    if (t == 0) {
        bucketBase[NBUK] = E;
        off[NN] = E;
    }
}

// bin edges into bucket regions at deterministic positions; pack src|dl<<20
__global__ __launch_bounds__(256) void binA_kernel(const int* __restrict__ src,
                                                   const int* __restrict__ dst,
                                                   const int* __restrict__ blockHist,
                                                   const int* __restrict__ bucketBase,
                                                   int* __restrict__ binned, int E) {
    __shared__ int cur[NBUK];
    __shared__ int lbase[NBUK];
    for (int i = threadIdx.x; i < NBUK; i += 256) {
        cur[i] = 0;
        lbase[i] = bucketBase[i] + blockHist[(size_t)i * ABLK + blockIdx.x];
    }
    __syncthreads();
    int base = blockIdx.x * ACH;
    int end = min(base + ACH, E);
    for (int e = base + threadIdx.x; e < end; e += 256) {
        int d = dst[e];
        int b = d >> 7;
        int r = atomicAdd(&cur[b], 1);
        binned[lbase[b] + r] = src[e] | ((d & 127) << 20);
    }
}

// per bucket: local counting sort -> csr (coalesced), deg -> ideg/off
__global__ __launch_bounds__(256) void bucketB_kernel(const int* __restrict__ binned,
                                                      const int* __restrict__ bucketBase,
                                                      int* __restrict__ csr,
                                                      int* __restrict__ off,
                                                      float* __restrict__ ideg, int N) {
    __shared__ int pair[2048];
    __shared__ int stage[4096];
    __shared__ int deg[128], loff[128], cur[128];
    int b = blockIdx.x, t = threadIdx.x;
    int e0 = bucketBase[b], e1 = bucketBase[b + 1];
    int cnt = e1 - e0;
    if (t < 128) deg[t] = 0;
    __syncthreads();
    for (int c0 = 0; c0 < cnt; c0 += 2048) {
        int cc = min(2048, cnt - c0);
        for (int i = t; i < cc; i += 256) pair[i] = binned[e0 + c0 + i];
        __syncthreads();
        for (int i = t; i < cc; i += 256) atomicAdd(&deg[pair[i] >> 20], 1);
        __syncthreads();
    }
    if (t < 128) loff[t] = deg[t];
    __syncthreads();
    for (int o = 1; o < 128; o <<= 1) {
        int u = (t < 128 && t >= o) ? loff[t - o] : 0;
        __syncthreads();
        if (t < 128) loff[t] += u;
        __syncthreads();
    }
    int nodeBase = b * 128;
    if (t < 128) {
        int ex = loff[t] - deg[t];
        cur[t] = ex;
        int n = nodeBase + t;
        if (n < N) {
            off[n] = e0 + ex;
            ideg[n] = 1.0f / (float)max(deg[t], 1);
        }
    }
    __syncthreads();
    if (cnt <= 4096) {
        for (int c0 = 0; c0 < cnt; c0 += 2048) {
            int cc = min(2048, cnt - c0);
            for (int i = t; i < cc; i += 256) pair[i] = binned[e0 + c0 + i];
            __syncthreads();
            for (int i = t; i < cc; i += 256) {
                int p = pair[i];
                int r = atomicAdd(&cur[p >> 20], 1);
                stage[r] = p & 0xFFFFF;
            }
            __syncthreads();
        }
        for (int i = t; i < cnt; i += 256) csr[e0 + i] = stage[i];
    } else {
        for (int c0 = 0; c0 < cnt; c0 += 2048) {
            int cc = min(2048, cnt - c0);
            for (int i = t; i < cc; i += 256) pair[i] = binned[e0 + c0 + i];
            __syncthreads();
            for (int i = t; i < cc; i += 256) {
                int p = pair[i];
                int r = atomicAdd(&cur[p >> 20], 1);
                csr[e0 + r] = p & 0xFFFFF;
            }
            __syncthreads();
        }
    }
}

// ---- weight transpose+convert: WT[c][k] bf16, c in [0,2*OUT) -----------
template <int OUT>
__global__ void wt_kernel(const float* __restrict__ Wl, const float* __restrict__ Wr,
                          short* __restrict__ WT) {
    int idx = blockIdx.x * 256 + threadIdx.x;
    if (idx >= 2 * OUT * 128) return;
    int c = idx >> 7, k = idx & 127;
    float v = (c < OUT) ? Wl[k * OUT + c] : Wr[k * OUT + (c - OUT)];
    WT[idx] = f2bf(v);
}

// ---- MFMA dual GEMM: P(bf16) = h@Wl, Q(f32) = h@Wr + b -----------------
template <int OUT>
__global__ __launch_bounds__(256) void sage_gemm_mfma(
    const float* __restrict__ h, const short* __restrict__ WT,
    const float* __restrict__ bias,
    short* __restrict__ P, float* __restrict__ Q, int N) {
    constexpr int K = 128;
    constexpr int NT = OUT / 32;

    const int tid = threadIdx.x;
    const int w = tid >> 6;
    const int lane = tid & 63;
    const int l15 = lane & 15;
    const int lhi = lane >> 4;
    const int rowBase = blockIdx.x * 64;
    const int colBase = w * (OUT / 2);
    const bool isQ = (w >= 2);
    const int qcolBase = colBase - OUT;

    f32x4 acc[4][NT];
#pragma unroll
    for (int mt = 0; mt < 4; ++mt)
#pragma unroll
        for (int nt = 0; nt < NT; ++nt) acc[mt][nt] = (f32x4){0.f, 0.f, 0.f, 0.f};

#pragma unroll
    for (int kt = 0; kt < 4; ++kt) {
        const int k0 = kt * 32 + lhi * 8;
        short8 a[4], b[NT];
#pragma unroll
        for (int mt = 0; mt < 4; ++mt) {
            int r = rowBase + mt * 16 + l15;
            r = min(r, N - 1);
            const float* hp = h + (size_t)r * K + k0;
            float4 v0 = *(const float4*)hp;
            float4 v1 = *(const float4*)(hp + 4);
            a[mt][0] = f2bf(v0.x); a[mt][1] = f2bf(v0.y);
            a[mt][2] = f2bf(v0.z); a[mt][3] = f2bf(v0.w);
            a[mt][4] = f2bf(v1.x); a[mt][5] = f2bf(v1.y);
            a[mt][6] = f2bf(v1.z); a[mt][7] = f2bf(v1.w);
        }
#pragma unroll
        for (int nt = 0; nt < NT; ++nt)
            b[nt] = *(const short8*)(WT + (size_t)(colBase + nt * 16 + l15) * K + k0);
#pragma unroll
        for (int mt = 0; mt < 4; ++mt)
#pragma unroll
            for (int nt = 0; nt < NT; ++nt)
                acc[mt][nt] = __builtin_amdgcn_mfma_f32_16x16x32_bf16(a[mt], b[nt], acc[mt][nt], 0, 0, 0);
    }

    if (!isQ) {
#pragma unroll
        for (int mt = 0; mt < 4; ++mt) {
#pragma unroll
            for (int nt = 0; nt < NT; ++nt) {
                int col = colBase + nt * 16 + l15;
#pragma unroll
                for (int rg = 0; rg < 4; ++rg) {
                    int row = rowBase + mt * 16 + lhi * 4 + rg;
                    if (row < N) P[(size_t)row * OUT + col] = f2bf(acc[mt][nt][rg]);
                }
            }
        }
    } else {
        float bj[NT];
#pragma unroll
        for (int nt = 0; nt < NT; ++nt) bj[nt] = bias[qcolBase + nt * 16 + l15];
#pragma unroll
        for (int mt = 0; mt < 4; ++mt) {
#pragma unroll
            for (int nt = 0; nt < NT; ++nt) {
                int col = qcolBase + nt * 16 + l15;
#pragma unroll
                for (int rg = 0; rg < 4; ++rg) {
                    int row = rowBase + mt * 16 + lhi * 4 + rg;
                    if (row < N) Q[(size_t)row * OUT + col] = acc[mt][nt][rg] + bj[nt];
                }
            }
        }
    }
}

// ---- CSR gather: Q[n] = relu?(Q[n] + ideg[n] * sum P[src]) -------------
template <int F, bool RELU>
__global__ __launch_bounds__(256) void gather_kernel(
    const int* __restrict__ csr, const int* __restrict__ off,
    const short* __restrict__ P, const float* __restrict__ ideg,
    float* __restrict__ Q, int N) {
    constexpr int C = F / 4;
    int t = blockIdx.x * blockDim.x + threadIdx.x;
    int n = t / C, c = t % C;
    if (n >= N) return;
    int e0 = off[n], e1 = off[n + 1];

    float ax = 0.f, ay = 0.f, az = 0.f, aw = 0.f;
    int e = e0;
    for (; e + 4 <= e1; e += 4) {
        int s0 = csr[e + 0], s1 = csr[e + 1], s2 = csr[e + 2], s3 = csr[e + 3];
        ushort4v u0 = *(const ushort4v*)(P + (size_t)s0 * F + c * 4);
        ushort4v u1 = *(const ushort4v*)(P + (size_t)s1 * F + c * 4);
        ushort4v u2 = *(const ushort4v*)(P + (size_t)s2 * F + c * 4);
        ushort4v u3 = *(const ushort4v*)(P + (size_t)s3 * F + c * 4);
        ax += (bf2f(u0[0]) + bf2f(u1[0])) + (bf2f(u2[0]) + bf2f(u3[0]));
        ay += (bf2f(u0[1]) + bf2f(u1[1])) + (bf2f(u2[1]) + bf2f(u3[1]));
        az += (bf2f(u0[2]) + bf2f(u1[2])) + (bf2f(u2[2]) + bf2f(u3[2]));
        aw += (bf2f(u0[3]) + bf2f(u1[3])) + (bf2f(u2[3]) + bf2f(u3[3]));
    }
    for (; e < e1; ++e) {
        int s = csr[e];
        ushort4v u = *(const ushort4v*)(P + (size_t)s * F + c * 4);
        ax += bf2f(u[0]); ay += bf2f(u[1]); az += bf2f(u[2]); aw += bf2f(u[3]);
    }

    float sc = ideg[n];
    float4 q = ((const float4*)(Q + (size_t)n * F))[c];
    q.x = fmaf(ax, sc, q.x);
    q.y = fmaf(ay, sc, q.y);
    q.z = fmaf(az, sc, q.z);
    q.w = fmaf(aw, sc, q.w);
    if (RELU) {
        q.x = fmaxf(q.x, 0.f); q.y = fmaxf(q.y, 0.f);
        q.z = fmaxf(q.z, 0.f); q.w = fmaxf(q.w, 0.f);
    }
    ((float4*)(Q + (size_t)n * F))[c] = q;
}

// ---- global mean pool --------------------------------------------------
__global__ __launch_bounds__(256) void pool_kernel(const float* __restrict__ h,
                                                   const int* __restrict__ batch,
                                                   float* __restrict__ gsum,
                                                   float* __restrict__ gcnt, int N) {
    __shared__ float ls[NG * 64];
    __shared__ float lc[NG];
    const int tid = threadIdx.x;
    for (int i = tid; i < NG * 64; i += 256) ls[i] = 0.f;
    if (tid < NG) lc[tid] = 0.f;
    __syncthreads();

    const int j = tid & 63;
    const int nl = tid >> 6;
    const int base = blockIdx.x * 256;
    for (int i = nl; i < 256; i += 4) {
        int n = base + i;
        if (n < N) {
            int g = batch[n];
            atomicAdd(&ls[g * 64 + j], h[(size_t)n * 64 + j]);
            if (j == 0) atomicAdd(&lc[g], 1.f);
        }
    }
    __syncthreads();
    for (int i = tid; i < NG * 64; i += 256) {
        float v = ls[i];
        if (v != 0.f) unsafeAtomicAdd(&gsum[i], v);
    }
    if (tid < NG) {
        float c = lc[tid];
        if (c != 0.f) unsafeAtomicAdd(&gcnt[tid], c);
    }
}

__global__ void final_kernel(const float* __restrict__ gsum, const float* __restrict__ gcnt,
                             float* __restrict__ out) {
    int t = blockIdx.x * blockDim.x + threadIdx.x;
    if (t < NG * 64) out[t] = gsum[t] / fmaxf(gcnt[t >> 6], 1.0f);
}

// ---- launch ------------------------------------------------------------
extern "C" void kernel_launch(void* const* d_in, const int* in_sizes, int n_in,
                              void* d_out, int out_size, void* d_ws, size_t ws_size,
                              hipStream_t stream) {
    const float* x     = (const float*)d_in[0];
    const int*   ei    = (const int*)d_in[1];
    const int*   batch = (const int*)d_in[2];
    const float* Wl0 = (const float*)d_in[4];
    const float* Wr0 = (const float*)d_in[5];
    const float* b0  = (const float*)d_in[6];
    const float* Wl1 = (const float*)d_in[7];
    const float* Wr1 = (const float*)d_in[8];
    const float* b1  = (const float*)d_in[9];
    const float* Wl2 = (const float*)d_in[10];
    const float* Wr2 = (const float*)d_in[11];
    const float* b2  = (const float*)d_in[12];

    const int N = NN, E = NE;
    const int* src = ei;
    const int* dst = ei + E;

    const size_t BUF = (size_t)NN * 128 * sizeof(float);  // 51.2 MB
    char* ws = (char*)d_ws;
    float* bufA = (float*)(ws);
    float* bufB = (float*)(ws + BUF);
    short* bufP = (short*)(ws + 2 * BUF);
    char* p = ws + 2 * BUF + (size_t)NN * 128 * 2;
    short* WT0  = (short*)p;        p += 256 * 128 * 2;
    short* WT1  = (short*)p;        p += 256 * 128 * 2;
    short* WT2  = (short*)p;        p += 128 * 128 * 2;
    float* ideg = (float*)p;        p += (size_t)N * 4;
    int* off    = (int*)p;          p += (size_t)(N + 4) * 4;
    int* blockHist = (int*)p;       p += (size_t)NBUK * ABLK * 4 + 16;
    int* bucketTot = (int*)p;       p += 784 * 4;
    int* bucketBase= (int*)p;       p += 784 * 4;
    float* gsum = (float*)p;        p += (size_t)NG * 64 * 4;
    float* gcnt = (float*)p;        p += (size_t)NG * 4;
    int* binned = (int*)p;          p += (size_t)E * 4;
    int* csr    = (int*)p;          p += (size_t)E * 4;

    hipMemsetAsync(gsum, 0, (size_t)(NG * 64 + NG) * sizeof(float), stream);

    // CSR build (deterministic bucket sort)
    histA_kernel<<<ABLK, 256, 0, stream>>>(dst, blockHist, E);
    scanBlk_kernel<<<NBUK, 128, 0, stream>>>(blockHist, bucketTot);
    scanTot_kernel<<<1, 1024, 0, stream>>>(bucketTot, bucketBase, off, E);
    binA_kernel<<<ABLK, 256, 0, stream>>>(src, dst, blockHist, bucketBase, binned, E);
    bucketB_kernel<<<NBUK, 256, 0, stream>>>(binned, bucketBase, csr, off, ideg, N);

    // weights -> bf16 transposed
    wt_kernel<128><<<cdiv(2 * 128 * 128, 256), 256, 0, stream>>>(Wl0, Wr0, WT0);
    wt_kernel<128><<<cdiv(2 * 128 * 128, 256), 256, 0, stream>>>(Wl1, Wr1, WT1);
    wt_kernel<64><<<cdiv(2 * 64 * 128, 256), 256, 0, stream>>>(Wl2, Wr2, WT2);

    const int GB = cdiv(N, 64);

    // Layer 0
    sage_gemm_mfma<128><<<GB, 256, 0, stream>>>(x, WT0, b0, bufP, bufA, N);
    gather_kernel<128, true><<<cdiv(N * 32, 256), 256, 0, stream>>>(csr, off, bufP, ideg, bufA, N);
    // Layer 1
    sage_gemm_mfma<128><<<GB, 256, 0, stream>>>(bufA, WT1, b1, bufP, bufB, N);
    gather_kernel<128, true><<<cdiv(N * 32, 256), 256, 0, stream>>>(csr, off, bufP, ideg, bufB, N);
    // Layer 2 (no relu)
    sage_gemm_mfma<64><<<GB, 256, 0, stream>>>(bufB, WT2, b2, bufP, bufA, N);
    gather_kernel<64, false><<<cdiv(N * 16, 256), 256, 0, stream>>>(csr, off, bufP, ideg, bufA, N);

    // Pool
    pool_kernel<<<cdiv(N, 256), 256, 0, stream>>>(bufA, batch, gsum, gcnt, N);
    final_kernel<<<16, 256, 0, stream>>>(gsum, gcnt, (float*)d_out);
}

// Round 5
// 401.930 us; speedup vs baseline: 18.1113x; 1.1191x over previous
//
#include <hip/hip_runtime.h>
#include <hip/hip_bf16.h>

#define NN 100000
#define NE 1600000
#define NG 64
#define NBUK 782   // cdiv(NN,128)
#define ABLK 98    // binning blocks
#define ACH 16384  // edges per binning block

typedef short short8 __attribute__((ext_vector_type(8)));
typedef float f32x4 __attribute__((ext_vector_type(4)));
typedef unsigned short ushort8v __attribute__((ext_vector_type(8)));

static inline int cdiv(int a, int b) { return (a + b - 1) / b; }

__device__ __forceinline__ short f2bf(float f) {
    return __builtin_bit_cast(short, __float2bfloat16(f));
}
__device__ __forceinline__ float bf2f(unsigned short u) {
    unsigned int x = ((unsigned int)u) << 16;
    return __builtin_bit_cast(float, x);
}

// ---- x -> bf16 ----------------------------------------------------------
__global__ __launch_bounds__(256) void xcvt_kernel(const float* __restrict__ x,
                                                   short* __restrict__ xb, int n8) {
    int i = blockIdx.x * 256 + threadIdx.x;
    if (i >= n8) return;
    const float4 v0 = ((const float4*)x)[i * 2];
    const float4 v1 = ((const float4*)x)[i * 2 + 1];
    short8 o;
    o[0] = f2bf(v0.x); o[1] = f2bf(v0.y); o[2] = f2bf(v0.z); o[3] = f2bf(v0.w);
    o[4] = f2bf(v1.x); o[5] = f2bf(v1.y); o[6] = f2bf(v1.z); o[7] = f2bf(v1.w);
    ((short8*)xb)[i] = o;
}

// ---- bucketed CSR build (no global atomics) ----------------------------
__global__ __launch_bounds__(256) void histA_kernel(const int* __restrict__ dst,
                                                    int* __restrict__ blockHist, int E) {
    __shared__ int h[NBUK];
    for (int i = threadIdx.x; i < NBUK; i += 256) h[i] = 0;
    __syncthreads();
    int base = blockIdx.x * ACH;
    int end = min(base + ACH, E);
    for (int e = base + threadIdx.x; e < end; e += 256) atomicAdd(&h[dst[e] >> 7], 1);
    __syncthreads();
    for (int i = threadIdx.x; i < NBUK; i += 256) blockHist[(size_t)i * ABLK + blockIdx.x] = h[i];
}

__global__ __launch_bounds__(128) void scanBlk_kernel(int* __restrict__ blockHist,
                                                      int* __restrict__ bucketTot) {
    __shared__ int s[128];
    int b = blockIdx.x, t = threadIdx.x;
    int v = (t < ABLK) ? blockHist[(size_t)b * ABLK + t] : 0;
    s[t] = v;
    __syncthreads();
    for (int o = 1; o < 128; o <<= 1) {
        int u = (t >= o) ? s[t - o] : 0;
        __syncthreads();
        s[t] += u;
        __syncthreads();
    }
    if (t < ABLK) blockHist[(size_t)b * ABLK + t] = s[t] - v;
    if (t == 127) bucketTot[b] = s[127];
}

__global__ __launch_bounds__(1024) void scanTot_kernel(const int* __restrict__ bucketTot,
                                                       int* __restrict__ bucketBase,
                                                       int* __restrict__ off, int E) {
    __shared__ int s[1024];
    int t = threadIdx.x;
    int v = (t < NBUK) ? bucketTot[t] : 0;
    s[t] = v;
    __syncthreads();
    for (int o = 1; o < 1024; o <<= 1) {
        int u = (t >= o) ? s[t - o] : 0;
        __syncthreads();
        s[t] += u;
        __syncthreads();
    }
    if (t < NBUK) bucketBase[t] = s[t] - v;
    if (t == 0) {
        bucketBase[NBUK] = E;
        off[NN] = E;
    }
}

__global__ __launch_bounds__(256) void binA_kernel(const int* __restrict__ src,
                                                   const int* __restrict__ dst,
                                                   const int* __restrict__ blockHist,
                                                   const int* __restrict__ bucketBase,
                                                   int* __restrict__ binned, int E) {
    __shared__ int cur[NBUK];
    __shared__ int lbase[NBUK];
    for (int i = threadIdx.x; i < NBUK; i += 256) {
        cur[i] = 0;
        lbase[i] = bucketBase[i] + blockHist[(size_t)i * ABLK + blockIdx.x];
    }
    __syncthreads();
    int base = blockIdx.x * ACH;
    int end = min(base + ACH, E);
    for (int e = base + threadIdx.x; e < end; e += 256) {
        int d = dst[e];
        int b = d >> 7;
        int r = atomicAdd(&cur[b], 1);
        binned[lbase[b] + r] = src[e] | ((d & 127) << 20);
    }
}

__global__ __launch_bounds__(256) void bucketB_kernel(const int* __restrict__ binned,
                                                      const int* __restrict__ bucketBase,
                                                      int* __restrict__ csr,
                                                      int* __restrict__ off,
                                                      float* __restrict__ ideg, int N) {
    __shared__ int pair[2048];
    __shared__ int stage[4096];
    __shared__ int deg[128], loff[128], cur[128];
    int b = blockIdx.x, t = threadIdx.x;
    int e0 = bucketBase[b], e1 = bucketBase[b + 1];
    int cnt = e1 - e0;
    if (t < 128) deg[t] = 0;
    __syncthreads();
    for (int c0 = 0; c0 < cnt; c0 += 2048) {
        int cc = min(2048, cnt - c0);
        for (int i = t; i < cc; i += 256) pair[i] = binned[e0 + c0 + i];
        __syncthreads();
        for (int i = t; i < cc; i += 256) atomicAdd(&deg[pair[i] >> 20], 1);
        __syncthreads();
    }
    if (t < 128) loff[t] = deg[t];
    __syncthreads();
    for (int o = 1; o < 128; o <<= 1) {
        int u = (t < 128 && t >= o) ? loff[t - o] : 0;
        __syncthreads();
        if (t < 128) loff[t] += u;
        __syncthreads();
    }
    int nodeBase = b * 128;
    if (t < 128) {
        int ex = loff[t] - deg[t];
        cur[t] = ex;
        int n = nodeBase + t;
        if (n < N) {
            off[n] = e0 + ex;
            ideg[n] = 1.0f / (float)max(deg[t], 1);
        }
    }
    __syncthreads();
    if (cnt <= 4096) {
        for (int c0 = 0; c0 < cnt; c0 += 2048) {
            int cc = min(2048, cnt - c0);
            for (int i = t; i < cc; i += 256) pair[i] = binned[e0 + c0 + i];
            __syncthreads();
            for (int i = t; i < cc; i += 256) {
                int p = pair[i];
                int r = atomicAdd(&cur[p >> 20], 1);
                stage[r] = p & 0xFFFFF;
            }
            __syncthreads();
        }
        for (int i = t; i < cnt; i += 256) csr[e0 + i] = stage[i];
    } else {
        for (int c0 = 0; c0 < cnt; c0 += 2048) {
            int cc = min(2048, cnt - c0);
            for (int i = t; i < cc; i += 256) pair[i] = binned[e0 + c0 + i];
            __syncthreads();
            for (int i = t; i < cc; i += 256) {
                int p = pair[i];
                int r = atomicAdd(&cur[p >> 20], 1);
                csr[e0 + r] = p & 0xFFFFF;
            }
            __syncthreads();
        }
    }
}

// ---- weight transpose+convert: WT[c][k] bf16, c in [0,2*OUT) -----------
template <int OUT>
__global__ void wt_kernel(const float* __restrict__ Wl, const float* __restrict__ Wr,
                          short* __restrict__ WT) {
    int idx = blockIdx.x * 256 + threadIdx.x;
    if (idx >= 2 * OUT * 128) return;
    int c = idx >> 7, k = idx & 127;
    float v = (c < OUT) ? Wl[k * OUT + c] : Wr[k * OUT + (c - OUT)];
    WT[idx] = f2bf(v);
}

// ---- MFMA dual GEMM: P(bf16) = h@Wl, Q(bf16) = h@Wr + b ----------------
// h: [N][128] bf16. WT: [2*OUT][128] bf16. Block: 4 waves, 64 rows.
template <int OUT>
__global__ __launch_bounds__(256) void sage_gemm_mfma(
    const short* __restrict__ h, const short* __restrict__ WT,
    const float* __restrict__ bias,
    short* __restrict__ P, short* __restrict__ Q, int N) {
    constexpr int K = 128;
    constexpr int NT = OUT / 32;

    const int tid = threadIdx.x;
    const int w = tid >> 6;
    const int lane = tid & 63;
    const int l15 = lane & 15;
    const int lhi = lane >> 4;
    const int rowBase = blockIdx.x * 64;
    const int colBase = w * (OUT / 2);
    const bool isQ = (w >= 2);
    const int qcolBase = colBase - OUT;

    f32x4 acc[4][NT];
#pragma unroll
    for (int mt = 0; mt < 4; ++mt)
#pragma unroll
        for (int nt = 0; nt < NT; ++nt) acc[mt][nt] = (f32x4){0.f, 0.f, 0.f, 0.f};

#pragma unroll
    for (int kt = 0; kt < 4; ++kt) {
        const int k0 = kt * 32 + lhi * 8;
        short8 a[4], b[NT];
#pragma unroll
        for (int mt = 0; mt < 4; ++mt) {
            int r = rowBase + mt * 16 + l15;
            r = min(r, N - 1);
            a[mt] = *(const short8*)(h + (size_t)r * K + k0);
        }
#pragma unroll
        for (int nt = 0; nt < NT; ++nt)
            b[nt] = *(const short8*)(WT + (size_t)(colBase + nt * 16 + l15) * K + k0);
#pragma unroll
        for (int mt = 0; mt < 4; ++mt)
#pragma unroll
            for (int nt = 0; nt < NT; ++nt)
                acc[mt][nt] = __builtin_amdgcn_mfma_f32_16x16x32_bf16(a[mt], b[nt], acc[mt][nt], 0, 0, 0);
    }

    if (!isQ) {
#pragma unroll
        for (int mt = 0; mt < 4; ++mt) {
#pragma unroll
            for (int nt = 0; nt < NT; ++nt) {
                int col = colBase + nt * 16 + l15;
#pragma unroll
                for (int rg = 0; rg < 4; ++rg) {
                    int row = rowBase + mt * 16 + lhi * 4 + rg;
                    if (row < N) P[(size_t)row * OUT + col] = f2bf(acc[mt][nt][rg]);
                }
            }
        }
    } else {
        float bj[NT];
#pragma unroll
        for (int nt = 0; nt < NT; ++nt) bj[nt] = bias[qcolBase + nt * 16 + l15];
#pragma unroll
        for (int mt = 0; mt < 4; ++mt) {
#pragma unroll
            for (int nt = 0; nt < NT; ++nt) {
                int col = qcolBase + nt * 16 + l15;
#pragma unroll
                for (int rg = 0; rg < 4; ++rg) {
                    int row = rowBase + mt * 16 + lhi * 4 + rg;
                    if (row < N) Q[(size_t)row * OUT + col] = f2bf(acc[mt][nt][rg] + bj[nt]);
                }
            }
        }
    }
}

// ---- CSR gather: hout[n] = relu?(Q[n] + ideg[n] * sum P[src]) ----------
// 16 (F=128) or 8 (F=64) threads per node; short8 (16B) per-edge loads.
template <int F, bool RELU>
__global__ __launch_bounds__(256) void gather_kernel(
    const int* __restrict__ csr, const int* __restrict__ off,
    const short* __restrict__ P, const float* __restrict__ ideg,
    const short* __restrict__ Qin, short* __restrict__ hout, int N) {
    constexpr int C = F / 8;  // threads per node row
    int t = blockIdx.x * blockDim.x + threadIdx.x;
    int n = t / C, c = t % C;
    if (n >= N) return;
    int e0 = off[n], e1 = off[n + 1];

    float f[8];
#pragma unroll
    for (int j = 0; j < 8; ++j) f[j] = 0.f;

    int e = e0;
    for (; e + 4 <= e1; e += 4) {
        int s0 = csr[e + 0], s1 = csr[e + 1], s2 = csr[e + 2], s3 = csr[e + 3];
        ushort8v u0 = *(const ushort8v*)(P + (size_t)s0 * F + c * 8);
        ushort8v u1 = *(const ushort8v*)(P + (size_t)s1 * F + c * 8);
        ushort8v u2 = *(const ushort8v*)(P + (size_t)s2 * F + c * 8);
        ushort8v u3 = *(const ushort8v*)(P + (size_t)s3 * F + c * 8);
#pragma unroll
        for (int j = 0; j < 8; ++j)
            f[j] += (bf2f(u0[j]) + bf2f(u1[j])) + (bf2f(u2[j]) + bf2f(u3[j]));
    }
    for (; e < e1; ++e) {
        int s = csr[e];
        ushort8v u = *(const ushort8v*)(P + (size_t)s * F + c * 8);
#pragma unroll
        for (int j = 0; j < 8; ++j) f[j] += bf2f(u[j]);
    }

    float sc = ideg[n];
    ushort8v q = *(const ushort8v*)(Qin + (size_t)n * F + c * 8);
    short8 o;
#pragma unroll
    for (int j = 0; j < 8; ++j) {
        float v = fmaf(f[j], sc, bf2f(q[j]));
        if (RELU) v = fmaxf(v, 0.f);
        o[j] = f2bf(v);
    }
    *(short8*)(hout + (size_t)n * F + c * 8) = o;
}

// ---- global mean pool (bf16 input) --------------------------------------
__global__ __launch_bounds__(256) void pool_kernel(const unsigned short* __restrict__ h,
                                                   const int* __restrict__ batch,
                                                   float* __restrict__ gsum,
                                                   float* __restrict__ gcnt, int N) {
    __shared__ float ls[NG * 64];
    __shared__ float lc[NG];
    const int tid = threadIdx.x;
    for (int i = tid; i < NG * 64; i += 256) ls[i] = 0.f;
    if (tid < NG) lc[tid] = 0.f;
    __syncthreads();

    const int j = tid & 63;
    const int nl = tid >> 6;
    const int base = blockIdx.x * 256;
    for (int i = nl; i < 256; i += 4) {
        int n = base + i;
        if (n < N) {
            int g = batch[n];
            atomicAdd(&ls[g * 64 + j], bf2f(h[(size_t)n * 64 + j]));
            if (j == 0) atomicAdd(&lc[g], 1.f);
        }
    }
    __syncthreads();
    for (int i = tid; i < NG * 64; i += 256) {
        float v = ls[i];
        if (v != 0.f) unsafeAtomicAdd(&gsum[i], v);
    }
    if (tid < NG) {
        float c = lc[tid];
        if (c != 0.f) unsafeAtomicAdd(&gcnt[tid], c);
    }
}

__global__ void final_kernel(const float* __restrict__ gsum, const float* __restrict__ gcnt,
                             float* __restrict__ out) {
    int t = blockIdx.x * blockDim.x + threadIdx.x;
    if (t < NG * 64) out[t] = gsum[t] / fmaxf(gcnt[t >> 6], 1.0f);
}

// ---- launch ------------------------------------------------------------
extern "C" void kernel_launch(void* const* d_in, const int* in_sizes, int n_in,
                              void* d_out, int out_size, void* d_ws, size_t ws_size,
                              hipStream_t stream) {
    const float* x     = (const float*)d_in[0];
    const int*   ei    = (const int*)d_in[1];
    const int*   batch = (const int*)d_in[2];
    const float* Wl0 = (const float*)d_in[4];
    const float* Wr0 = (const float*)d_in[5];
    const float* b0  = (const float*)d_in[6];
    const float* Wl1 = (const float*)d_in[7];
    const float* Wr1 = (const float*)d_in[8];
    const float* b1  = (const float*)d_in[9];
    const float* Wl2 = (const float*)d_in[10];
    const float* Wr2 = (const float*)d_in[11];
    const float* b2  = (const float*)d_in[12];

    const int N = NN, E = NE;
    const int* src = ei;
    const int* dst = ei + E;

    const size_t HB = (size_t)NN * 128 * 2;  // 25.6 MB bf16 buffer
    char* ws = (char*)d_ws;
    short* xbf  = (short*)(ws);
    short* hA   = (short*)(ws + HB);
    short* hB   = (short*)(ws + 2 * HB);
    short* bufP = (short*)(ws + 3 * HB);
    short* bufQ = (short*)(ws + 4 * HB);
    char* p = ws + 5 * HB;
    short* WT0  = (short*)p;        p += 256 * 128 * 2;
    short* WT1  = (short*)p;        p += 256 * 128 * 2;
    short* WT2  = (short*)p;        p += 128 * 128 * 2;
    float* ideg = (float*)p;        p += (size_t)N * 4;
    int* off    = (int*)p;          p += (size_t)(N + 4) * 4;
    int* blockHist = (int*)p;       p += (size_t)NBUK * ABLK * 4 + 16;
    int* bucketTot = (int*)p;       p += 784 * 4;
    int* bucketBase= (int*)p;       p += 784 * 4;
    float* gsum = (float*)p;        p += (size_t)NG * 64 * 4;
    float* gcnt = (float*)p;        p += (size_t)NG * 4;
    int* binned = (int*)p;          p += (size_t)E * 4;
    int* csr    = (int*)p;          p += (size_t)E * 4;

    hipMemsetAsync(gsum, 0, (size_t)(NG * 64 + NG) * sizeof(float), stream);

    // CSR build (deterministic bucket sort)
    histA_kernel<<<ABLK, 256, 0, stream>>>(dst, blockHist, E);
    scanBlk_kernel<<<NBUK, 128, 0, stream>>>(blockHist, bucketTot);
    scanTot_kernel<<<1, 1024, 0, stream>>>(bucketTot, bucketBase, off, E);
    binA_kernel<<<ABLK, 256, 0, stream>>>(src, dst, blockHist, bucketBase, binned, E);
    bucketB_kernel<<<NBUK, 256, 0, stream>>>(binned, bucketBase, csr, off, ideg, N);

    // weights -> bf16 transposed; x -> bf16
    wt_kernel<128><<<cdiv(2 * 128 * 128, 256), 256, 0, stream>>>(Wl0, Wr0, WT0);
    wt_kernel<128><<<cdiv(2 * 128 * 128, 256), 256, 0, stream>>>(Wl1, Wr1, WT1);
    wt_kernel<64><<<cdiv(2 * 64 * 128, 256), 256, 0, stream>>>(Wl2, Wr2, WT2);
    xcvt_kernel<<<cdiv(N * 128 / 8, 256), 256, 0, stream>>>(x, xbf, N * 128 / 8);

    const int GB = cdiv(N, 64);

    // Layer 0
    sage_gemm_mfma<128><<<GB, 256, 0, stream>>>(xbf, WT0, b0, bufP, bufQ, N);
    gather_kernel<128, true><<<cdiv(N * 16, 256), 256, 0, stream>>>(csr, off, bufP, ideg, bufQ, hA, N);
    // Layer 1
    sage_gemm_mfma<128><<<GB, 256, 0, stream>>>(hA, WT1, b1, bufP, bufQ, N);
    gather_kernel<128, true><<<cdiv(N * 16, 256), 256, 0, stream>>>(csr, off, bufP, ideg, bufQ, hB, N);
    // Layer 2 (no relu)
    sage_gemm_mfma<64><<<GB, 256, 0, stream>>>(hB, WT2, b2, bufP, bufQ, N);
    gather_kernel<64, false><<<cdiv(N * 8, 256), 256, 0, stream>>>(csr, off, bufP, ideg, bufQ, hA, N);

    // Pool
    pool_kernel<<<cdiv(N, 256), 256, 0, stream>>>((const unsigned short*)hA, batch, gsum, gcnt, N);
    final_kernel<<<16, 256, 0, stream>>>(gsum, gcnt, (float*)d_out);
}